// Round 5
// baseline (540.638 us; speedup 1.0000x reference)
//
#include <hip/hip_runtime.h>
#include <hip/hip_bf16.h>

// Problem constants: B=8, N=2048, D=384, R=64, H=W=256.
// Inputs:  x (B,N,D) f32, segments (B,H,W) i32, prototypes (1,R,D) f32.
// Outputs (f32, concat): out (B,N,D) | segments (B,H,W) | loss (1) | C (B,N,R)
//
// Memory plan:
//  * prox bitmask (2048 bits/node) lives INSIDE the out chunk: node n's mask
//    occupies the first 64 u32 of its own 1536-byte output row. k_pool reads
//    its own row's mask (wave-local) before overwriting that row.
//  * rawS -> s -> C computed IN PLACE (f32) in the outC chunk.
//  * cinv (1/||C_n||) borrows the outSeg chunk; k_segout runs last.
//  * d_ws use: kn + mask + colsum + lossacc only (~100 KB).
#define NB 8
#define NN 2048
#define ND 384
#define NR 64
#define OUT_ELEMS (NB*NN*ND)        // 6291456
#define SEG_ELEMS (NB*256*256)      // 524288
#define POOL_CAP 512                // per-wave neighbor list capacity (deg <= ~4*pixels/seg ~ 240 max)

__device__ inline float wsum(float v){
  #pragma unroll
  for(int o=32;o;o>>=1) v += __shfl_xor(v,o,64);
  return v;
}
__device__ inline float wmax(float v){
  #pragma unroll
  for(int o=32;o;o>>=1) v = fmaxf(v,__shfl_xor(v,o,64));
  return v;
}

// ---- normalize prototypes -> kn (f32, unit rows) ----
__global__ void k_proto(const float* __restrict__ protos, float* __restrict__ kn){
  int r = blockIdx.x, l = threadIdx.x;
  float v[6]; float ss = 0.f;
  #pragma unroll
  for(int i=0;i<6;i++){ v[i] = protos[r*ND + l*6 + i]; ss += v[i]*v[i]; }
  ss = wsum(ss);
  float inv = 1.f / fmaxf(sqrtf(ss), 1e-8f);
  #pragma unroll
  for(int i=0;i<6;i++) kn[r*ND + l*6 + i] = v[i]*inv;
}

// ---- segments -> node mask (ws) + prox bits (into out-chunk rows) ----
__global__ void k_seg(const int* __restrict__ seg, float* __restrict__ mask, unsigned* proxv){
  int idx = blockIdx.x*256 + threadIdx.x;         // < B*H*W = 524288
  int b = idx >> 16, p = idx & 65535, i = p >> 8, j = p & 255;
  int s = seg[idx];
  int base = b << 11;                              // b*N
  mask[base + s] = 1.f;                            // benign race: same value
  if(j < 255){
    int s2 = seg[idx+1];
    if(s != s2 && s != 0 && s2 != 0){
      atomicOr(&proxv[(base+s)*ND  + (s2>>5)], 1u<<(s2&31));
      atomicOr(&proxv[(base+s2)*ND + (s >>5)], 1u<<(s &31));
    }
  }
  if(i < 255){
    int s2 = seg[idx+256];
    if(s != s2 && s != 0 && s2 != 0){
      atomicOr(&proxv[(base+s)*ND  + (s2>>5)], 1u<<(s2&31));
      atomicOr(&proxv[(base+s2)*ND + (s >>5)], 1u<<(s &31));
    }
  }
}

// ---- Csim GEMM (xinv fused): rawS[node][r] = (dot(x_n,kn_r)/max(||x_n||,eps)+1)/2 ----
__global__ __launch_bounds__(256) void k_csim(const float* __restrict__ x,
                                              const float* __restrict__ kn,
                                              float* __restrict__ Sout){
  __shared__ float xT[32*68];
  __shared__ float kT[32*68];
  __shared__ float xinvS[64];
  int t = threadIdx.x;
  int m0 = blockIdx.x * 64;
  float acc[4][4] = {};
  int mload = t>>2, koff = (t&3)*8;
  int mb = (t>>4)*4, rb = (t&15)*4;
  float ssq = 0.f;
  for(int c=0;c<12;c++){
    int k0 = c*32;
    __syncthreads();
    const float4* xg = (const float4*)(x + (m0+mload)*ND + k0 + koff);
    float4 a = xg[0], bq = xg[1];
    ssq += a.x*a.x + a.y*a.y + a.z*a.z + a.w*a.w
         + bq.x*bq.x + bq.y*bq.y + bq.z*bq.z + bq.w*bq.w;
    xT[(koff+0)*68+mload]=a.x;  xT[(koff+1)*68+mload]=a.y;  xT[(koff+2)*68+mload]=a.z;  xT[(koff+3)*68+mload]=a.w;
    xT[(koff+4)*68+mload]=bq.x; xT[(koff+5)*68+mload]=bq.y; xT[(koff+6)*68+mload]=bq.z; xT[(koff+7)*68+mload]=bq.w;
    const float4* kg = (const float4*)(kn + mload*ND + k0 + koff);
    float4 ka = kg[0], kb = kg[1];
    kT[(koff+0)*68+mload]=ka.x; kT[(koff+1)*68+mload]=ka.y; kT[(koff+2)*68+mload]=ka.z; kT[(koff+3)*68+mload]=ka.w;
    kT[(koff+4)*68+mload]=kb.x; kT[(koff+5)*68+mload]=kb.y; kT[(koff+6)*68+mload]=kb.z; kT[(koff+7)*68+mload]=kb.w;
    __syncthreads();
    for(int k=0;k<32;k++){
      float xv[4], kv[4];
      *(float4*)xv = *(const float4*)&xT[k*68+mb];
      *(float4*)kv = *(const float4*)&kT[k*68+rb];
      #pragma unroll
      for(int mi=0;mi<4;mi++)
        #pragma unroll
        for(int ri=0;ri<4;ri++) acc[mi][ri] += xv[mi]*kv[ri];
    }
  }
  // per-row ||x||: reduce over the 4 loader lanes of each row (consecutive lanes)
  ssq += __shfl_xor(ssq,1,64);
  ssq += __shfl_xor(ssq,2,64);
  if((t&3)==0) xinvS[mload] = 1.f / fmaxf(sqrtf(ssq), 1e-8f);
  __syncthreads();
  #pragma unroll
  for(int mi=0;mi<4;mi++){
    float xin = xinvS[mb+mi];
    #pragma unroll
    for(int ri=0;ri<4;ri++)
      Sout[(m0+mb+mi)*NR + rb + ri] = (acc[mi][ri]*xin + 1.f)*0.5f;
  }
}

// ---- fused: rawS -> normalized s (in place) + colsum partial ----
__global__ __launch_bounds__(256) void k_snorm(float* Smat, float* __restrict__ colsum){
  __shared__ float sh[256];
  int w = threadIdx.x>>6, l = threadIdx.x&63;
  int n0 = blockIdx.x*32 + w*8;                    // 32 nodes/block, one batch per block
  int b = (blockIdx.x*32) >> 11;
  float csacc = 0.f;
  for(int k=0;k<8;k++){
    int node = n0 + k;
    float raw = Smat[node*NR + l];
    float s = raw / wsum(raw);
    Smat[node*NR + l] = s;
    csacc += s;
  }
  sh[threadIdx.x] = csacc;
  __syncthreads();
  if(threadIdx.x < 64)
    atomicAdd(&colsum[(b<<6) + threadIdx.x],
              sh[threadIdx.x]+sh[threadIdx.x+64]+sh[threadIdx.x+128]+sh[threadIdx.x+192]);
}

// ---- fused: DEC KL loss partials + C=softmax(s) in place + cinv ----
__global__ void k_lossfc(float* Smat, const float* __restrict__ colsum,
                         const float* __restrict__ mask, float* __restrict__ lossacc,
                         float* __restrict__ cinv){
  __shared__ float shk[4], shm[4];
  int w = threadIdx.x>>6, l = threadIdx.x&63;
  int node = blockIdx.x*4 + w;
  int b = node >> 11;
  float s = Smat[node*NR + l];
  // loss
  float csm = colsum[(b<<6) + l];
  float p = s*s/(csm + 1e-8f);
  float ps = wsum(p);
  float P = p/(ps + 1e-8f);
  float term = P*(logf(P + 1e-8f) - logf(s + 1e-8f));
  float kl = wsum(term);
  if(l==0){ float mv = mask[node]; shk[w] = kl*mv; shm[w] = mv; }
  // softmax + norm
  float mx = wmax(s);
  float e = expf(s - mx);
  float Z = wsum(e);
  float c = e / Z;
  float cn2 = wsum(c*c);
  Smat[node*NR + l] = c;
  if(l==0) cinv[node] = 1.f/sqrtf(cn2);
  __syncthreads();
  if(threadIdx.x==0){
    atomicAdd(&lossacc[0], shk[0]+shk[1]+shk[2]+shk[3]);
    atomicAdd(&lossacc[1], shm[0]+shm[1]+shm[2]+shm[3]);
  }
}

__global__ void k_fin(const float* __restrict__ lossacc, float* __restrict__ outLoss){
  if(threadIdx.x==0) outLoss[0] = lossacc[0]/(lossacc[1]+1e-8f);
}

__global__ void k_segout(const int* __restrict__ seg, float* __restrict__ o){
  int i = blockIdx.x*256 + threadIdx.x;
  o[i] = (float)seg[i];
}

// ---- sparse fused pooling v2: one wave per row; 4 neighbors per iteration ----
// Decode the 2048-bit prox row into a compact LDS list, then each 16-lane group
// computes one neighbor's C.C dot (float4 + 4 shfl steps); broadcast wv,m to the
// wave for the x accumulation. Per-node cinv_n cancels; only cinv_m applied.
__global__ __launch_bounds__(256) void k_pool(const float* __restrict__ x,
                                              float* outb,
                                              const float* __restrict__ Cmat,
                                              const float* __restrict__ cinv){
  __shared__ unsigned short lists[4][POOL_CAP];
  int w = threadIdx.x>>6, l = threadIdx.x&63;
  int b = blockIdx.x & 7, nb = blockIdx.x >> 3;   // batch-major for L2/XCD locality
  int n = nb*4 + w;
  int node = (b<<11) + n;
  const unsigned* proxv = (const unsigned*)outb;
  unsigned word = proxv[node*ND + l];             // own row's 2048-bit mask
  if(l == (n>>5)) word |= 1u << (n&31);           // diagonal always present
  // exclusive prefix of per-lane popcounts -> compact index list (wave-local LDS)
  int cnt = __popc(word);
  int pre = cnt;
  #pragma unroll
  for(int o=1;o<64;o<<=1){ int t = __shfl_up(pre,o,64); if(l>=o) pre += t; }
  int total = __shfl(pre,63,64);
  pre -= cnt;
  unsigned short* lst = lists[w];
  {
    unsigned wtmp = word; int wp = pre, base = l<<5;
    while(wtmp){ int j=__builtin_ctz(wtmp); wtmp&=wtmp-1; if(wp<POOL_CAP) lst[wp]=(unsigned short)(base+j); wp++; }
  }
  if(total > POOL_CAP) total = POOL_CAP;          // unreachable for this input scale
  int t = l & 15, g = l >> 4;
  const float*  Cb  = Cmat + (b<<11)*NR;
  const float2* xb2 = (const float2*)(x + (size_t)(b<<11)*ND);
  const float*  civ = cinv + (b<<11);
  float4 cn4 = ((const float4*)(Cmat + (size_t)node*NR))[t];
  float a0=0,a1=0,a2=0,a3=0,a4=0,a5=0, rs=0;
  for(int i=0;i<total;i+=4){
    int slot = i + g;
    int m = (slot < total) ? (int)lst[slot] : -1;
    int mm = (m<0) ? 0 : m;
    float4 cg = ((const float4*)(Cb + mm*NR))[t];
    float d = cn4.x*cg.x + cn4.y*cg.y + cn4.z*cg.z + cn4.w*cg.w;
    #pragma unroll
    for(int o=1;o<16;o<<=1) d += __shfl_xor(d,o,64);  // 16-lane group reduce
    float wv = (m<0) ? 0.f : d * civ[mm];
    #pragma unroll
    for(int j=0;j<4;j++){
      float wvj = __shfl(wv, j*16, 64);
      int   mj  = __shfl(m,  j*16, 64);
      if(mj >= 0){                                   // wave-uniform branch
        rs += wvj;
        const float2* xr = xb2 + mj*(ND/2);
        float2 p0 = xr[l], p1 = xr[l+64], p2 = xr[l+128];
        a0 += wvj*p0.x; a1 += wvj*p0.y;
        a2 += wvj*p1.x; a3 += wvj*p1.y;
        a4 += wvj*p2.x; a5 += wvj*p2.y;
      }
    }
  }
  float inv = 1.f/(rs + 1e-8f);
  float2* orow2 = (float2*)(outb + (size_t)node*ND);
  orow2[l]     = make_float2(a0*inv, a1*inv);
  orow2[l+64]  = make_float2(a2*inv, a3*inv);
  orow2[l+128] = make_float2(a4*inv, a5*inv);
}

extern "C" void kernel_launch(void* const* d_in, const int* in_sizes, int n_in,
                              void* d_out, int out_size, void* d_ws, size_t ws_size,
                              hipStream_t stream) {
  const float* x      = (const float*)d_in[0];     // (B,N,D) f32
  const int*   seg    = (const int*)d_in[1];       // (B,H,W) i32
  const float* protos = (const float*)d_in[2];     // (1,R,D) f32

  float* out     = (float*)d_out;                  // (B,N,D)
  float* outSeg  = out + OUT_ELEMS;                // (B,H,W)
  float* outLoss = outSeg + SEG_ELEMS;             // scalar
  float* outC    = outLoss + 1;                    // (B,N,R)

  unsigned* proxv = (unsigned*)d_out;              // prox rows inside out chunk
  float*    cinv  = outSeg;                        // 16384 f32, overwritten by k_segout last

  float* ws      = (float*)d_ws;                   // total use: ~98.5 KB
  float* kn      = ws;                             // 24576 f32
  float* maskp   = kn + NR*ND;                     // 16384
  float* colsum  = maskp + NB*NN;                  // 512
  float* lossacc = colsum + NB*NR;                 // 2

  hipMemsetAsync(out, 0, (size_t)OUT_ELEMS*4, stream);                    // zero prox region
  hipMemsetAsync(maskp, 0, (size_t)(NB*NN + NB*NR + 2)*4, stream);        // mask+colsum+lossacc

  k_proto <<<dim3(NR),           dim3(64),  0, stream>>>(protos, kn);
  k_seg   <<<dim3(NB*65536/256), dim3(256), 0, stream>>>(seg, maskp, proxv);
  k_csim  <<<dim3(NB*NN/64),     dim3(256), 0, stream>>>(x, kn, outC);
  k_snorm <<<dim3(NB*NN/32),     dim3(256), 0, stream>>>(outC, colsum);
  k_lossfc<<<dim3(NB*NN/4),      dim3(256), 0, stream>>>(outC, colsum, maskp, lossacc, cinv);
  k_pool  <<<dim3(NB*NN/4),      dim3(256), 0, stream>>>(x, out, outC, cinv);
  k_fin   <<<dim3(1),            dim3(64),  0, stream>>>(lossacc, outLoss);
  k_segout<<<dim3(SEG_ELEMS/256),dim3(256), 0, stream>>>(seg, outSeg);
}

// Round 6
// 418.085 us; speedup vs baseline: 1.2931x; 1.2931x over previous
//
#include <hip/hip_runtime.h>
#include <hip/hip_bf16.h>

// B=8, N=2048, D=384, R=64, H=W=256.
// Inputs:  x (B,N,D) f32, segments (B,H,W) i32, prototypes (1,R,D) f32.
// Outputs (f32, concat): out (B,N,D) | segments (B,H,W) | loss (1) | C (B,N,R)
//
// k_pool = dense masked attention: out = rownorm((M .* (C Chat^T)) X) per batch,
// computed with mfma_f32_16x16x32_bf16. Q=C rows (f32->bf16), K=Chat bf16
// (cinv folded, written by k_lossfc), V=x via precomputed transposed bf16 xT
// (emitted by k_csim from its already-transposed LDS tile). Mask bits (prox)
// built by k_seg in d_ws, staged to LDS per tile. P does a C-layout -> LDS ->
// A-layout round trip (bf16); rowsum accumulated in C-layout f32.
#define NB 8
#define NN 2048
#define ND 384
#define NR 64
#define OUT_ELEMS (NB*NN*ND)        // 6291456
#define SEG_ELEMS (NB*256*256)      // 524288

typedef float  f32x4  __attribute__((ext_vector_type(4)));
typedef short  bf16x8 __attribute__((ext_vector_type(8)));

__device__ inline float wsum(float v){
  #pragma unroll
  for(int o=32;o;o>>=1) v += __shfl_xor(v,o,64);
  return v;
}
__device__ inline float wmax(float v){
  #pragma unroll
  for(int o=32;o;o>>=1) v = fmaxf(v,__shfl_xor(v,o,64));
  return v;
}
__device__ inline unsigned short f2bf(float f){
  unsigned u = __float_as_uint(f);
  return (unsigned short)((u + 0x8000u) >> 16);
}

// ---- normalize prototypes -> kn (f32, unit rows) ----
__global__ void k_proto(const float* __restrict__ protos, float* __restrict__ kn){
  int r = blockIdx.x, l = threadIdx.x;
  float v[6]; float ss = 0.f;
  #pragma unroll
  for(int i=0;i<6;i++){ v[i] = protos[r*ND + l*6 + i]; ss += v[i]*v[i]; }
  ss = wsum(ss);
  float inv = 1.f / fmaxf(sqrtf(ss), 1e-8f);
  #pragma unroll
  for(int i=0;i<6;i++) kn[r*ND + l*6 + i] = v[i]*inv;
}

// ---- segments -> node mask + prox bitmask rows (64 u32/node, in ws) ----
__global__ void k_seg(const int* __restrict__ seg, float* __restrict__ mask, unsigned* prox){
  int idx = blockIdx.x*256 + threadIdx.x;         // < B*H*W
  int b = idx >> 16, p = idx & 65535, i = p >> 8, j = p & 255;
  int s = seg[idx];
  int base = b << 11;
  mask[base + s] = 1.f;
  if(j < 255){
    int s2 = seg[idx+1];
    if(s != s2 && s != 0 && s2 != 0){
      atomicOr(&prox[((size_t)(base+s))*64  + (s2>>5)], 1u<<(s2&31));
      atomicOr(&prox[((size_t)(base+s2))*64 + (s >>5)], 1u<<(s &31));
    }
  }
  if(i < 255){
    int s2 = seg[idx+256];
    if(s != s2 && s != 0 && s2 != 0){
      atomicOr(&prox[((size_t)(base+s))*64  + (s2>>5)], 1u<<(s2&31));
      atomicOr(&prox[((size_t)(base+s2))*64 + (s >>5)], 1u<<(s &31));
    }
  }
}

// ---- Csim GEMM (xinv fused) + bf16 x-transpose emission ----
__global__ __launch_bounds__(256) void k_csim(const float* __restrict__ x,
                                              const float* __restrict__ kn,
                                              float* __restrict__ Sout,
                                              unsigned short* __restrict__ xTbf){
  __shared__ float xT[32*68];
  __shared__ float kT[32*68];
  __shared__ float xinvS[64];
  int t = threadIdx.x;
  int m0 = blockIdx.x * 64;                        // global node base (one batch)
  float acc[4][4] = {};
  int mload = t>>2, koff = (t&3)*8;
  int mb = (t>>4)*4, rb = (t&15)*4;
  float ssq = 0.f;
  for(int c=0;c<12;c++){
    int k0 = c*32;
    __syncthreads();
    const float4* xg = (const float4*)(x + (size_t)(m0+mload)*ND + k0 + koff);
    float4 a = xg[0], bq = xg[1];
    ssq += a.x*a.x + a.y*a.y + a.z*a.z + a.w*a.w
         + bq.x*bq.x + bq.y*bq.y + bq.z*bq.z + bq.w*bq.w;
    xT[(koff+0)*68+mload]=a.x;  xT[(koff+1)*68+mload]=a.y;  xT[(koff+2)*68+mload]=a.z;  xT[(koff+3)*68+mload]=a.w;
    xT[(koff+4)*68+mload]=bq.x; xT[(koff+5)*68+mload]=bq.y; xT[(koff+6)*68+mload]=bq.z; xT[(koff+7)*68+mload]=bq.w;
    const float4* kg = (const float4*)(kn + mload*ND + k0 + koff);
    float4 ka = kg[0], kb = kg[1];
    kT[(koff+0)*68+mload]=ka.x; kT[(koff+1)*68+mload]=ka.y; kT[(koff+2)*68+mload]=ka.z; kT[(koff+3)*68+mload]=ka.w;
    kT[(koff+4)*68+mload]=kb.x; kT[(koff+5)*68+mload]=kb.y; kT[(koff+6)*68+mload]=kb.z; kT[(koff+7)*68+mload]=kb.w;
    __syncthreads();
    // emit transposed bf16 chunk: xTbf[b][k0..k0+32][mtile 64]
    {
      int k2 = t>>3, mo = (t&7)*8;
      const float* src = &xT[k2*68 + mo];
      float4 aa = *(const float4*)src;
      float4 bb = *(const float4*)(src+4);
      uint4 o;
      o.x = (unsigned)f2bf(aa.x) | ((unsigned)f2bf(aa.y)<<16);
      o.y = (unsigned)f2bf(aa.z) | ((unsigned)f2bf(aa.w)<<16);
      o.z = (unsigned)f2bf(bb.x) | ((unsigned)f2bf(bb.y)<<16);
      o.w = (unsigned)f2bf(bb.z) | ((unsigned)f2bf(bb.w)<<16);
      int bb2 = m0 >> 11, ml = m0 & 2047;
      *(uint4*)(xTbf + ((size_t)(bb2*ND + k0 + k2))*NN + ml + mo) = o;
    }
    for(int k=0;k<32;k++){
      float xv[4], kv[4];
      *(float4*)xv = *(const float4*)&xT[k*68+mb];
      *(float4*)kv = *(const float4*)&kT[k*68+rb];
      #pragma unroll
      for(int mi=0;mi<4;mi++)
        #pragma unroll
        for(int ri=0;ri<4;ri++) acc[mi][ri] += xv[mi]*kv[ri];
    }
  }
  ssq += __shfl_xor(ssq,1,64);
  ssq += __shfl_xor(ssq,2,64);
  if((t&3)==0) xinvS[mload] = 1.f / fmaxf(sqrtf(ssq), 1e-8f);
  __syncthreads();
  #pragma unroll
  for(int mi=0;mi<4;mi++){
    float xin = xinvS[mb+mi];
    #pragma unroll
    for(int ri=0;ri<4;ri++)
      Sout[(size_t)(m0+mb+mi)*NR + rb + ri] = (acc[mi][ri]*xin + 1.f)*0.5f;
  }
}

// ---- rawS -> normalized s (in place) + colsum partial ----
__global__ __launch_bounds__(256) void k_snorm(float* Smat, float* __restrict__ colsum){
  __shared__ float sh[256];
  int w = threadIdx.x>>6, l = threadIdx.x&63;
  int n0 = blockIdx.x*32 + w*8;
  int b = (blockIdx.x*32) >> 11;
  float csacc = 0.f;
  for(int k=0;k<8;k++){
    int node = n0 + k;
    float raw = Smat[node*NR + l];
    float s = raw / wsum(raw);
    Smat[node*NR + l] = s;
    csacc += s;
  }
  sh[threadIdx.x] = csacc;
  __syncthreads();
  if(threadIdx.x < 64)
    atomicAdd(&colsum[(b<<6) + threadIdx.x],
              sh[threadIdx.x]+sh[threadIdx.x+64]+sh[threadIdx.x+128]+sh[threadIdx.x+192]);
}

// ---- DEC KL loss partials + C=softmax(s) in place + Kbf = bf16(C*cinv) ----
__global__ void k_lossfc(float* Smat, const float* __restrict__ colsum,
                         const float* __restrict__ mask, float* __restrict__ lossacc,
                         unsigned short* __restrict__ Kbf){
  __shared__ float shk[4], shm[4];
  int w = threadIdx.x>>6, l = threadIdx.x&63;
  int node = blockIdx.x*4 + w;
  int b = node >> 11;
  float s = Smat[node*NR + l];
  float csm = colsum[(b<<6) + l];
  float p = s*s/(csm + 1e-8f);
  float ps = wsum(p);
  float P = p/(ps + 1e-8f);
  float term = P*(logf(P + 1e-8f) - logf(s + 1e-8f));
  float kl = wsum(term);
  if(l==0){ float mv = mask[node]; shk[w] = kl*mv; shm[w] = mv; }
  float mx = wmax(s);
  float e = expf(s - mx);
  float Z = wsum(e);
  float c = e / Z;
  float cn2 = wsum(c*c);
  Smat[node*NR + l] = c;
  Kbf[(size_t)node*NR + l] = f2bf(c * rsqrtf(cn2));
  __syncthreads();
  if(threadIdx.x==0){
    atomicAdd(&lossacc[0], shk[0]+shk[1]+shk[2]+shk[3]);
    atomicAdd(&lossacc[1], shm[0]+shm[1]+shm[2]+shm[3]);
  }
}

__global__ void k_fin(const float* __restrict__ lossacc, float* __restrict__ outLoss){
  if(threadIdx.x==0) outLoss[0] = lossacc[0]/(lossacc[1]+1e-8f);
}

__global__ void k_segout(const int* __restrict__ seg, float* __restrict__ o){
  int i = blockIdx.x*256 + threadIdx.x;
  o[i] = (float)seg[i];
}

// ---- dense masked-attention pooling ----
// grid 512: b=bid&7 (XCD locality), nt=(bid>>3)&31 (64-row tile), ds=bid>>8 (192-col slice)
__global__ __launch_bounds__(256) void k_pool(const float* __restrict__ Cmat,
                                              const unsigned short* __restrict__ Kbf,
                                              const unsigned short* __restrict__ xTbf,
                                              const unsigned* __restrict__ prox,
                                              float* __restrict__ out){
  __shared__ unsigned prox_lds[64*66];   // stride 66: bank spread + 8B align
  __shared__ short    Plds[64*68];       // stride 68: conflict-free b16 writes
  __shared__ float    rsbuf[64];

  int tid = threadIdx.x;
  int w = tid>>6, l = tid&63, q = l>>4, li = l&15;
  int b  = blockIdx.x & 7;
  int r2 = blockIdx.x >> 3;
  int nt = r2 & 31, ds = r2 >> 5;
  int base = nt*64;
  int dsbase = ds*192 + w*48;

  // stage prox rows (+diagonal bit) into LDS
  {
    int i = tid>>2, wq = (tid&3)*16;
    int n = base + i;
    const unsigned* src = prox + ((size_t)(b*NN + n))*64 + wq;
    int dwd = n>>5;
    #pragma unroll
    for(int k2=0;k2<4;k2++){
      uint4 v = *(const uint4*)(src + k2*4);
      int w0 = wq + k2*4;
      if(w0   == dwd) v.x |= 1u<<(n&31);
      if(w0+1 == dwd) v.y |= 1u<<(n&31);
      if(w0+2 == dwd) v.z |= 1u<<(n&31);
      if(w0+3 == dwd) v.w |= 1u<<(n&31);
      *(uint2*)&prox_lds[i*66 + w0]     = make_uint2(v.x, v.y);
      *(uint2*)&prox_lds[i*66 + w0 + 2] = make_uint2(v.z, v.w);
    }
  }

  // Q fragments: wave's 16 rows, A-layout [n=li][r = c*32 + q*8 + j]
  bf16x8 qf[2];
  {
    int n = base + 16*w + li;
    const float* crow = Cmat + ((size_t)(b*NN + n))*NR;
    #pragma unroll
    for(int c=0;c<2;c++){
      float4 v0 = *(const float4*)(crow + c*32 + q*8);
      float4 v1 = *(const float4*)(crow + c*32 + q*8 + 4);
      bf16x8 a;
      a[0]=(short)f2bf(v0.x); a[1]=(short)f2bf(v0.y); a[2]=(short)f2bf(v0.z); a[3]=(short)f2bf(v0.w);
      a[4]=(short)f2bf(v1.x); a[5]=(short)f2bf(v1.y); a[6]=(short)f2bf(v1.z); a[7]=(short)f2bf(v1.w);
      qf[c]=a;
    }
  }
  __syncthreads();

  f32x4 oacc[4][3];
  #pragma unroll
  for(int nc=0;nc<4;nc++)
    #pragma unroll
    for(int t=0;t<3;t++) oacc[nc][t] = (f32x4)(0.f);
  float rsacc[4] = {0.f,0.f,0.f,0.f};

  const unsigned short* Kb  = Kbf  + (size_t)b*NN*NR;
  const unsigned short* xTb = xTbf + (size_t)b*ND*NN;

  for(int mt=0; mt<32; mt++){
    // phase 1: P rows for this wave (16 x 64), C-layout
    f32x4 pacc[4] = {(f32x4)(0.f),(f32x4)(0.f),(f32x4)(0.f),(f32x4)(0.f)};
    #pragma unroll
    for(int c=0;c<2;c++)
      #pragma unroll
      for(int f=0;f<4;f++){
        const bf16x8* kp = (const bf16x8*)(Kb + ((size_t)(mt*64 + f*16 + li))*NR + c*32 + q*8);
        pacc[f] = __builtin_amdgcn_mfma_f32_16x16x32_bf16(qf[c], *kp, pacc[f], 0,0,0);
      }
    // mask + rowsum + bf16 P -> LDS
    #pragma unroll
    for(int r=0;r<4;r++){
      int row = 16*w + q*4 + r;
      uint2 mw = *(const uint2*)&prox_lds[row*66 + mt*2];
      #pragma unroll
      for(int f=0;f<4;f++){
        unsigned wd = (f<2) ? mw.x : mw.y;
        float v = ((wd >> ((f&1)*16 + li)) & 1u) ? pacc[f][r] : 0.f;
        rsacc[r] += (row>>4)==w ? 0.f : 0.f;   // no-op guard removed by compiler
        rsacc[r] += v;
        Plds[row*68 + f*16 + li] = (short)f2bf(v);
      }
    }
    __syncthreads();
    // phase 2: O += P * V  (A from Plds, B from xT bf16)
    #pragma unroll
    for(int c=0;c<2;c++)
      #pragma unroll
      for(int nc=0;nc<4;nc++){
        const short* pr = &Plds[(nc*16 + li)*68 + c*32 + q*8];
        union { uint2 u2[2]; bf16x8 v; } af;
        af.u2[0] = *(const uint2*)pr;
        af.u2[1] = *(const uint2*)(pr+4);
        #pragma unroll
        for(int t=0;t<3;t++){
          const bf16x8* bp = (const bf16x8*)(xTb + ((size_t)(dsbase + t*16 + li))*NN + mt*64 + c*32 + q*8);
          oacc[nc][t] = __builtin_amdgcn_mfma_f32_16x16x32_bf16(af.v, *bp, oacc[nc][t], 0,0,0);
        }
      }
    __syncthreads();
  }

  // publish rowsums
  #pragma unroll
  for(int r=0;r<4;r++){
    float v = rsacc[r];
    v += __shfl_xor(v,1,64); v += __shfl_xor(v,2,64);
    v += __shfl_xor(v,4,64); v += __shfl_xor(v,8,64);
    if(li==0) rsbuf[16*w + q*4 + r] = v;
  }
  __syncthreads();
  // normalize + store
  #pragma unroll
  for(int nc=0;nc<4;nc++)
    #pragma unroll
    for(int r=0;r<4;r++){
      int n = nc*16 + q*4 + r;
      float inv = 1.f/(rsbuf[n] + 1e-8f);
      float* orow = out + ((size_t)(b*NN + base + n))*ND + dsbase;
      #pragma unroll
      for(int t=0;t<3;t++)
        orow[t*16 + li] = oacc[nc][t][r] * inv;
    }
}

extern "C" void kernel_launch(void* const* d_in, const int* in_sizes, int n_in,
                              void* d_out, int out_size, void* d_ws, size_t ws_size,
                              hipStream_t stream) {
  const float* x      = (const float*)d_in[0];
  const int*   seg    = (const int*)d_in[1];
  const float* protos = (const float*)d_in[2];

  float* out     = (float*)d_out;                  // (B,N,D)
  float* outSeg  = out + OUT_ELEMS;                // (B,H,W)
  float* outLoss = outSeg + SEG_ELEMS;             // scalar
  float* outC    = outLoss + 1;                    // (B,N,R)

  // ws layout (~18.2 MB total)
  unsigned short* xTbf = (unsigned short*)d_ws;            // 8*384*2048 bf16
  unsigned short* Kbf  = xTbf + (size_t)NB*ND*NN;          // 8*2048*64 bf16
  float* kn      = (float*)(Kbf + (size_t)NB*NN*NR);       // 24576 f32
  float* maskp   = kn + NR*ND;                             // 16384  -- zero region start
  float* colsum  = maskp + NB*NN;                          // 512
  float* lossacc = colsum + NB*NR;                         // 4 (pad to 16B)
  unsigned* prox = (unsigned*)(lossacc + 4);               // 8*2048*64 u32 (16B aligned)

  size_t zero_bytes = (size_t)(NB*NN + NB*NR + 4)*4 + (size_t)NB*NN*64*4;
  hipMemsetAsync(maskp, 0, zero_bytes, stream);

  k_proto <<<dim3(NR),           dim3(64),  0, stream>>>(protos, kn);
  k_seg   <<<dim3(NB*65536/256), dim3(256), 0, stream>>>(seg, maskp, prox);
  k_csim  <<<dim3(NB*NN/64),     dim3(256), 0, stream>>>(x, kn, outC, xTbf);
  k_snorm <<<dim3(NB*NN/32),     dim3(256), 0, stream>>>(outC, colsum);
  k_lossfc<<<dim3(NB*NN/4),      dim3(256), 0, stream>>>(outC, colsum, maskp, lossacc, Kbf);
  k_pool  <<<dim3(512),          dim3(256), 0, stream>>>(outC, Kbf, xTbf, prox, out);
  k_fin   <<<dim3(1),            dim3(64),  0, stream>>>(lossacc, outLoss);
  k_segout<<<dim3(SEG_ELEMS/256),dim3(256), 0, stream>>>(seg, outSeg);
}